// Round 1
// baseline (365.427 us; speedup 1.0000x reference)
//
#include <hip/hip_runtime.h>
#include <hip/hip_fp16.h>

typedef __attribute__((ext_vector_type(8))) _Float16 f16x8;
typedef __attribute__((ext_vector_type(4))) float f32x4;

#define M_DIM 8192
#define N_DIM 4096
#define K_DIM 4096
#define BM 128
#define BN 128
#define BK 32

__constant__ float FP4_LUT[16] = {0.f, 0.5f, 1.f, 1.5f, 2.f, 3.f, 4.f, 6.f,
                                  -0.f, -0.5f, -1.f, -1.5f, -2.f, -3.f, -4.f, -6.f};

__device__ inline void glds16(const void* g, void* l) {
    __builtin_amdgcn_global_load_lds(
        (const __attribute__((address_space(1))) void*)g,
        (__attribute__((address_space(3))) void*)l, 16, 0, 0);
}

// ---- prepass 1: x fp32 -> fp16 ----
__global__ __launch_bounds__(256) void cvt_x_kernel(const float* __restrict__ x,
                                                    _Float16* __restrict__ xh) {
    int i = (blockIdx.x * 256 + threadIdx.x) * 8;
    const float4* p = (const float4*)(x + i);
    float4 a = p[0], b = p[1];
    f16x8 h;
    h[0] = (_Float16)a.x; h[1] = (_Float16)a.y;
    h[2] = (_Float16)a.z; h[3] = (_Float16)a.w;
    h[4] = (_Float16)b.x; h[5] = (_Float16)b.y;
    h[6] = (_Float16)b.z; h[7] = (_Float16)b.w;
    *(f16x8*)(xh + i) = h;
}

// ---- prepass 2: packed fp4 bytes (as int32) -> fp16 W[N][K] row-major ----
__global__ __launch_bounds__(256) void dequant_w_kernel(const int* __restrict__ w,
                                                        const float* __restrict__ wsc,
                                                        _Float16* __restrict__ wh) {
    int t = blockIdx.x * 256 + threadIdx.x;   // one thread = 4 packed bytes = 8 elems
    int4 b4 = ((const int4*)w)[t];
    int o  = t >> 9;                 // row, 512 int4-groups per row (2048 bytes)
    int j0 = (t & 511) << 2;         // byte column 0..2044 (multiple of 4)
    float s = wsc[(o << 8) + (j0 >> 3)];   // block = 16 elems = 8 bytes; j0%8 in {0,4}
    f16x8 h;
    int b;
    b = b4.x; h[0] = (_Float16)(FP4_LUT[(b >> 4) & 15] * s); h[1] = (_Float16)(FP4_LUT[b & 15] * s);
    b = b4.y; h[2] = (_Float16)(FP4_LUT[(b >> 4) & 15] * s); h[3] = (_Float16)(FP4_LUT[b & 15] * s);
    b = b4.z; h[4] = (_Float16)(FP4_LUT[(b >> 4) & 15] * s); h[5] = (_Float16)(FP4_LUT[b & 15] * s);
    b = b4.w; h[6] = (_Float16)(FP4_LUT[(b >> 4) & 15] * s); h[7] = (_Float16)(FP4_LUT[b & 15] * s);
    *(f16x8*)(wh + ((long)o << 12) + (j0 << 1)) = h;
}

// ---- main GEMM: C[M,N] = A[M,K] * B[N,K]^T + bias ----
__global__ __launch_bounds__(256) void gemm_f16_kernel(const _Float16* __restrict__ A,
                                                       const _Float16* __restrict__ B,
                                                       const float* __restrict__ bias,
                                                       float* __restrict__ C) {
    __shared__ _Float16 As[BM * BK];   // 8 KB, row-major [128][32], 64 B rows
    __shared__ _Float16 Bs[BN * BK];   // 8 KB

    const int tid  = threadIdx.x;
    const int wid  = tid >> 6;
    const int lane = tid & 63;
    const int lrow = lane & 15;     // row (A) / col (B) within 16x16 frag
    const int kgrp = lane >> 4;     // k-group: k = kgrp*8 + j
    const int wm = wid >> 1, wn = wid & 1;   // 2x2 waves, each 64x64 out

    const int brow = blockIdx.y * BM;
    const int bcol = blockIdx.x * BN;

    // staging: 256 thr x 16 B = 4 KB per issue = 64 rows of 64 B
    const int srow = tid >> 2;            // 0..63
    const int scol = (tid & 3) << 3;      // half-elements 0,8,16,24
    const _Float16* agp0 = A + (long)(brow + srow) * K_DIM + scol;
    const _Float16* agp1 = A + (long)(brow + 64 + srow) * K_DIM + scol;
    const _Float16* bgp0 = B + (long)(bcol + srow) * K_DIM + scol;
    const _Float16* bgp1 = B + (long)(bcol + 64 + srow) * K_DIM + scol;

    // LDS dest: wave-uniform base; HW adds lane*16 B
    _Float16* alds0 = As + wid * 512;
    _Float16* alds1 = As + 2048 + wid * 512;
    _Float16* blds0 = Bs + wid * 512;
    _Float16* blds1 = Bs + 2048 + wid * 512;

    f32x4 acc[4][4] = {};

    for (int k0 = 0; k0 < K_DIM; k0 += BK) {
        glds16(agp0 + k0, alds0);
        glds16(agp1 + k0, alds1);
        glds16(bgp0 + k0, blds0);
        glds16(bgp1 + k0, blds1);
        __syncthreads();   // compiler drains vmcnt before barrier

        f16x8 a[4], b[4];
#pragma unroll
        for (int m = 0; m < 4; ++m)
            a[m] = *(const f16x8*)(As + (wm * 64 + m * 16 + lrow) * BK + kgrp * 8);
#pragma unroll
        for (int n = 0; n < 4; ++n)
            b[n] = *(const f16x8*)(Bs + (wn * 64 + n * 16 + lrow) * BK + kgrp * 8);
#pragma unroll
        for (int m = 0; m < 4; ++m)
#pragma unroll
            for (int n = 0; n < 4; ++n)
                acc[m][n] = __builtin_amdgcn_mfma_f32_16x16x32_f16(a[m], b[n], acc[m][n], 0, 0, 0);
        __syncthreads();
    }

    // epilogue: C/D layout col = lane&15, row = (lane>>4)*4 + reg
#pragma unroll
    for (int m = 0; m < 4; ++m) {
        int row = brow + wm * 64 + m * 16 + kgrp * 4;
#pragma unroll
        for (int n = 0; n < 4; ++n) {
            int col = bcol + wn * 64 + n * 16 + lrow;
            float bv = bias[col];
#pragma unroll
            for (int j = 0; j < 4; ++j)
                C[(long)(row + j) * N_DIM + col] = acc[m][n][j] + bv;
        }
    }
}

// ---- fallback (only if ws too small): naive on-the-fly dequant dot ----
__global__ __launch_bounds__(256) void fallback_kernel(const float* __restrict__ x,
                                                       const int* __restrict__ w,
                                                       const float* __restrict__ wsc,
                                                       const float* __restrict__ bias,
                                                       float* __restrict__ out) {
    long idx = (long)blockIdx.x * 256 + threadIdx.x;
    int t = (int)(idx >> 12);
    int o = (int)(idx & 4095);
    float acc = 0.f;
    for (int j = 0; j < K_DIM / 2; ++j) {
        int b = w[o * (K_DIM / 2) + j];
        float s = wsc[(o << 8) + (j >> 3)];
        acc += x[(long)t * K_DIM + 2 * j]     * (FP4_LUT[(b >> 4) & 15] * s);
        acc += x[(long)t * K_DIM + 2 * j + 1] * (FP4_LUT[b & 15] * s);
    }
    out[idx] = acc + bias[o];
}

extern "C" void kernel_launch(void* const* d_in, const int* in_sizes, int n_in,
                              void* d_out, int out_size, void* d_ws, size_t ws_size,
                              hipStream_t stream) {
    const float* x    = (const float*)d_in[0];
    const int*   w    = (const int*)d_in[1];
    const float* wsc  = (const float*)d_in[2];
    const float* bias = (const float*)d_in[3];
    float* out = (float*)d_out;

    const size_t xh_bytes = (size_t)M_DIM * K_DIM * 2;   // 64 MB
    const size_t wh_bytes = (size_t)N_DIM * K_DIM * 2;   // 32 MB

    if (ws_size >= xh_bytes + wh_bytes) {
        _Float16* xh = (_Float16*)d_ws;
        _Float16* wh = (_Float16*)((char*)d_ws + xh_bytes);
        cvt_x_kernel<<<(M_DIM * K_DIM) / (256 * 8), 256, 0, stream>>>(x, xh);
        dequant_w_kernel<<<(N_DIM * (K_DIM / 2)) / (256 * 4), 256, 0, stream>>>(w, wsc, wh);
        dim3 grid(N_DIM / BN, M_DIM / BM);
        gemm_f16_kernel<<<grid, 256, 0, stream>>>(xh, wh, bias, out);
    } else {
        fallback_kernel<<<((long)M_DIM * N_DIM) / 256, 256, 0, stream>>>(x, w, wsc, bias, out);
    }
}

// Round 2
// 309.311 us; speedup vs baseline: 1.1814x; 1.1814x over previous
//
#include <hip/hip_runtime.h>
#include <hip/hip_fp16.h>

typedef __attribute__((ext_vector_type(8))) _Float16 f16x8;
typedef __attribute__((ext_vector_type(4))) float f32x4;

#define M_DIM 8192
#define N_DIM 4096
#define K_DIM 4096
#define BM 256
#define BN 256
#define BK 32
#define NT (K_DIM / BK)              // 128 K-tiles
#define TILE_F16 ((BM + BN) * BK)    // 16384 f16 = 32 KB per ring slot

__constant__ float FP4_LUT[16] = {0.f, 0.5f, 1.f, 1.5f, 2.f, 3.f, 4.f, 6.f,
                                  -0.f, -0.5f, -1.f, -1.5f, -2.f, -3.f, -4.f, -6.f};

__device__ inline void glds16(const void* g, void* l) {
    __builtin_amdgcn_global_load_lds(
        (const __attribute__((address_space(1))) void*)g,
        (__attribute__((address_space(3))) void*)l, 16, 0, 0);
}

// ---- prepass 1: x fp32 -> fp16 ----
__global__ __launch_bounds__(256) void cvt_x_kernel(const float* __restrict__ x,
                                                    _Float16* __restrict__ xh) {
    int i = (blockIdx.x * 256 + threadIdx.x) * 8;
    const float4* p = (const float4*)(x + i);
    float4 a = p[0], b = p[1];
    f16x8 h;
    h[0] = (_Float16)a.x; h[1] = (_Float16)a.y;
    h[2] = (_Float16)a.z; h[3] = (_Float16)a.w;
    h[4] = (_Float16)b.x; h[5] = (_Float16)b.y;
    h[6] = (_Float16)b.z; h[7] = (_Float16)b.w;
    *(f16x8*)(xh + i) = h;
}

// ---- prepass 2: packed fp4 bytes -> fp16 W[N][K] row-major ----
__global__ __launch_bounds__(256) void dequant_w_kernel(const int* __restrict__ w,
                                                        const float* __restrict__ wsc,
                                                        _Float16* __restrict__ wh) {
    int t = blockIdx.x * 256 + threadIdx.x;   // one thread = 4 packed bytes = 8 elems
    int4 b4 = ((const int4*)w)[t];
    int o  = t >> 9;
    int j0 = (t & 511) << 2;
    float s = wsc[(o << 8) + (j0 >> 3)];
    f16x8 h;
    int b;
    b = b4.x; h[0] = (_Float16)(FP4_LUT[(b >> 4) & 15] * s); h[1] = (_Float16)(FP4_LUT[b & 15] * s);
    b = b4.y; h[2] = (_Float16)(FP4_LUT[(b >> 4) & 15] * s); h[3] = (_Float16)(FP4_LUT[b & 15] * s);
    b = b4.z; h[4] = (_Float16)(FP4_LUT[(b >> 4) & 15] * s); h[5] = (_Float16)(FP4_LUT[b & 15] * s);
    b = b4.w; h[6] = (_Float16)(FP4_LUT[(b >> 4) & 15] * s); h[7] = (_Float16)(FP4_LUT[b & 15] * s);
    *(f16x8*)(wh + ((long)o << 12) + (j0 << 1)) = h;
}

// ---- main GEMM: C[M,N] = A[M,K] * B[N,K]^T + bias ----
// 256x256 tile, 8 waves (2Mx4N, 128x64 per wave), BK=32, 4-deep LDS ring,
// counted vmcnt (T4), 1 barrier/K-tile (T3-lite), XOR swizzle (T2),
// XCD block swizzle (T1), setprio (T5).
__global__ __launch_bounds__(512, 2) void gemm_f16_pipe(const _Float16* __restrict__ A,
                                                        const _Float16* __restrict__ B,
                                                        const float* __restrict__ bias,
                                                        float* __restrict__ C) {
    __shared__ _Float16 lds[4 * TILE_F16];   // 128 KiB

    const int tid  = threadIdx.x;
    const int wid  = tid >> 6;
    const int lane = tid & 63;
    const int fr   = lane & 15;      // fragment row/col within 16
    const int kg   = lane >> 4;      // k-group 0..3
    const int wm   = wid >> 2;       // 0..1
    const int wn   = wid & 3;        // 0..3

    // T1: XCD-aware swizzle. 512 blocks, 64/XCD chunk, column-major in chunk:
    // consecutive blocks in a chunk share the 2 MB B-panel (fits 4 MB XCD L2).
    int bid = blockIdx.x;
    int nb  = (bid & 7) * 64 + (bid >> 3);
    int bm  = nb & 31;
    int bn  = nb >> 5;
    const int brow = bm * BM;
    const int bcol = bn * BN;

    // ---- staging geometry (one glds16 issue = 512thr*16B = 128 rows x 64 B) ----
    // linear LDS offset L = tid*16 within issue; row = L>>6, swizzled col16 = (lane&3);
    // logical col16 = (lane&3) ^ ((row>>1)&3) with (row>>1)&3 = (lane>>3)&3.
    const int s_r = (wid << 4) + (lane >> 2);                    // 0..127
    const int s_c = (((lane & 3) ^ ((lane >> 3) & 3)) << 3);     // f16 col, pre-swizzled src

    const _Float16* srcA0 = A + (size_t)(brow +       s_r) * K_DIM + s_c;
    const _Float16* srcA1 = A + (size_t)(brow + 128 + s_r) * K_DIM + s_c;
    const _Float16* srcB0 = B + (size_t)(bcol +       s_r) * K_DIM + s_c;
    const _Float16* srcB1 = B + (size_t)(bcol + 128 + s_r) * K_DIM + s_c;

    // wave-uniform LDS dest offsets (f16 units)
    const int dA0 = (wid << 9);
    const int dA1 = 4096  + (wid << 9);
    const int dB0 = 8192  + (wid << 9);
    const int dB1 = 12288 + (wid << 9);

    // ---- read addressing (T2 swizzle: col16 ^= (row>>1)&3; row%16 == fr) ----
    const int swz    = ((kg ^ ((fr >> 1) & 3)) << 3);
    const int a_base = (wm * 128 + fr) * BK + swz;              // + m*16*BK
    const int b_base = BM * BK + (wn * 64 + fr) * BK + swz;     // + n*16*BK

    f32x4 acc[8][4] = {};

    // prologue: stage tiles 0..2 (12 loads in flight)
#pragma unroll
    for (int p = 0; p < 3; ++p) {
        _Float16* db = lds + p * TILE_F16;
        size_t kk = (size_t)p * BK;
        glds16(srcA0 + kk, db + dA0);
        glds16(srcA1 + kk, db + dA1);
        glds16(srcB0 + kk, db + dB0);
        glds16(srcB1 + kk, db + dB1);
    }

    for (int t = 0; t < NT; ++t) {
        // T4: counted vmcnt — retire exactly tile t's 4 loads (oldest), never 0
        // until the tail. Then one barrier: all waves' tile-t loads landed.
        if (t + 2 < NT)      asm volatile("s_waitcnt vmcnt(8)" ::: "memory");
        else if (t + 1 < NT) asm volatile("s_waitcnt vmcnt(4)" ::: "memory");
        else                 asm volatile("s_waitcnt vmcnt(0)" ::: "memory");
        __builtin_amdgcn_s_barrier();
        __builtin_amdgcn_sched_barrier(0);   // keep ds_reads below the barrier

        // stage tile t+3 into buf[(t+3)&3] — that slot's last reads were in
        // iteration t-1, drained before the barrier above (WAR-safe).
        if (t + 3 < NT) {
            _Float16* db = lds + ((t + 3) & 3) * TILE_F16;
            size_t kk = (size_t)(t + 3) * BK;
            glds16(srcA0 + kk, db + dA0);
            glds16(srcA1 + kk, db + dA1);
            glds16(srcB0 + kk, db + dB0);
            glds16(srcB1 + kk, db + dB1);
        }

        const _Float16* cb = lds + (t & 3) * TILE_F16;
        f16x8 af[8], bf[4];
#pragma unroll
        for (int m = 0; m < 8; ++m)
            af[m] = *(const f16x8*)(cb + a_base + m * (16 * BK));
#pragma unroll
        for (int n = 0; n < 4; ++n)
            bf[n] = *(const f16x8*)(cb + b_base + n * (16 * BK));

        __builtin_amdgcn_s_setprio(1);
#pragma unroll
        for (int m = 0; m < 8; ++m)
#pragma unroll
            for (int n = 0; n < 4; ++n)
                acc[m][n] = __builtin_amdgcn_mfma_f32_16x16x32_f16(af[m], bf[n], acc[m][n], 0, 0, 0);
        __builtin_amdgcn_s_setprio(0);
    }

    // epilogue: C/D layout col = lane&15, row = (lane>>4)*4 + reg
#pragma unroll
    for (int m = 0; m < 8; ++m) {
        int row = brow + wm * 128 + m * 16 + kg * 4;
#pragma unroll
        for (int n = 0; n < 4; ++n) {
            int col = bcol + wn * 64 + n * 16 + fr;
            float bv = bias[col];
#pragma unroll
            for (int j = 0; j < 4; ++j)
                C[(size_t)(row + j) * N_DIM + col] = acc[m][n][j] + bv;
        }
    }
}

// ---- fallback (only if ws too small) ----
__global__ __launch_bounds__(256) void fallback_kernel(const float* __restrict__ x,
                                                       const int* __restrict__ w,
                                                       const float* __restrict__ wsc,
                                                       const float* __restrict__ bias,
                                                       float* __restrict__ out) {
    long idx = (long)blockIdx.x * 256 + threadIdx.x;
    int t = (int)(idx >> 12);
    int o = (int)(idx & 4095);
    float acc = 0.f;
    for (int j = 0; j < K_DIM / 2; ++j) {
        int b = w[o * (K_DIM / 2) + j];
        float s = wsc[(o << 8) + (j >> 3)];
        acc += x[(long)t * K_DIM + 2 * j]     * (FP4_LUT[(b >> 4) & 15] * s);
        acc += x[(long)t * K_DIM + 2 * j + 1] * (FP4_LUT[b & 15] * s);
    }
    out[idx] = acc + bias[o];
}

extern "C" void kernel_launch(void* const* d_in, const int* in_sizes, int n_in,
                              void* d_out, int out_size, void* d_ws, size_t ws_size,
                              hipStream_t stream) {
    const float* x    = (const float*)d_in[0];
    const int*   w    = (const int*)d_in[1];
    const float* wsc  = (const float*)d_in[2];
    const float* bias = (const float*)d_in[3];
    float* out = (float*)d_out;

    const size_t xh_bytes = (size_t)M_DIM * K_DIM * 2;   // 64 MB
    const size_t wh_bytes = (size_t)N_DIM * K_DIM * 2;   // 32 MB

    if (ws_size >= xh_bytes + wh_bytes) {
        _Float16* xh = (_Float16*)d_ws;
        _Float16* wh = (_Float16*)((char*)d_ws + xh_bytes);
        cvt_x_kernel<<<(M_DIM * K_DIM) / (256 * 8), 256, 0, stream>>>(x, xh);
        dequant_w_kernel<<<(N_DIM * (K_DIM / 2)) / (256 * 4), 256, 0, stream>>>(w, wsc, wh);
        gemm_f16_pipe<<<(M_DIM / BM) * (N_DIM / BN), 512, 0, stream>>>(xh, wh, bias, out);
    } else {
        fallback_kernel<<<((long)M_DIM * N_DIM) / 256, 256, 0, stream>>>(x, w, wsc, bias, out);
    }
}